// Round 10
// baseline (1242.825 us; speedup 1.0000x reference)
//
#include <hip/hip_runtime.h>
#include <cstdint>
#include <cstddef>

namespace {
constexpr int kL = 16;                    // levels
constexpr uint32_t kT = 1u << 19;         // hash table entries per level
constexpr uint32_t kTmask = kT - 1u;
constexpr uint32_t kP1 = 2654435761u;     // spatial hash primes
constexpr uint32_t kP2 = 805459861u;

// native clang vectors: __builtin_nontemporal_* requires these
// (HIP float4/float2 are class types -> rejected by the builtin)
typedef float vfloat4 __attribute__((ext_vector_type(4)));
typedef float vfloat2 __attribute__((ext_vector_type(2)));
}

// Per-point prep: everything except the gathers (indices + weights).
struct Prep {
    uint32_t idx[8];
    float w[8];
};

__device__ __forceinline__ void prep_point(float px, float py, float pz,
                                           float fres, Prep& pr) {
    // scale, floor, frac (fp32 ops match the reference exactly)
    const float xs0 = px * fres;
    const float xs1 = py * fres;
    const float xs2 = pz * fres;
    const float fl0 = floorf(xs0);
    const float fl1 = floorf(xs1);
    const float fl2 = floorf(xs2);
    const float fx = xs0 - fl0;
    const float fy = xs1 - fl1;
    const float fz = xs2 - fl2;
    const uint32_t i0 = (uint32_t)(int)fl0;
    const uint32_t i1 = (uint32_t)(int)fl1;
    const uint32_t i2 = (uint32_t)(int)fl2;

    // factored hash: h(c0,c1,c2) = c0 ^ c1*P1 ^ c2*P2 (uint32 wrap)
    const uint32_t h0a = i0;
    const uint32_t h0b = i0 + 1u;
    const uint32_t h1a = i1 * kP1;
    const uint32_t h1b = (i1 + 1u) * kP1;
    const uint32_t h2a = i2 * kP2;
    const uint32_t h2b = (i2 + 1u) * kP2;

    pr.idx[0] = (h0a ^ h1a ^ h2a) & kTmask;
    pr.idx[1] = (h0a ^ h1a ^ h2b) & kTmask;
    pr.idx[2] = (h0a ^ h1b ^ h2a) & kTmask;
    pr.idx[3] = (h0a ^ h1b ^ h2b) & kTmask;
    pr.idx[4] = (h0b ^ h1a ^ h2a) & kTmask;
    pr.idx[5] = (h0b ^ h1a ^ h2b) & kTmask;
    pr.idx[6] = (h0b ^ h1b ^ h2a) & kTmask;
    pr.idx[7] = (h0b ^ h1b ^ h2b) & kTmask;

    const float wx0 = 1.0f - fx, wx1 = fx;
    const float wy0 = 1.0f - fy, wy1 = fy;
    const float wz0 = 1.0f - fz, wz1 = fz;
    pr.w[0] = wx0 * wy0 * wz0;
    pr.w[1] = wx0 * wy0 * wz1;
    pr.w[2] = wx0 * wy1 * wz0;
    pr.w[3] = wx0 * wy1 * wz1;
    pr.w[4] = wx1 * wy0 * wz0;
    pr.w[5] = wx1 * wy0 * wz1;
    pr.w[6] = wx1 * wy1 * wz0;
    pr.w[7] = wx1 * wy1 * wz1;
}

// ---------------------------------------------------------------------------
// Level-major pass, 2 points per thread. GPU-wide working set = ONE 4MB
// table -> L2-resident per XCD by construction.
//
// Round-10 change (round-9 intent, fixed to compile): ALL streaming
// accesses (x reads, ws writes) are non-temporal (`nt` evict-first) so
// the per-XCD L2 is reserved for the 4MB table. Theory: the x stream +
// ws stream were evicting table lines (8x avg reuse) -> HBM re-fetch;
// level kernels ran ~69us vs the ~31us L2-BW/TA-issue floor.
// ---------------------------------------------------------------------------
template <int RES, int LVL>
__global__ __launch_bounds__(256) void hashgrid_level2(
    const float* __restrict__ x,         // [P,3]
    const float* __restrict__ hashmap,   // [L,T,F] f32
    float2* __restrict__ ws2,            // [kL][P] float2
    int P)
{
    const int t = blockIdx.x * 256 + threadIdx.x;
    const int p0 = 2 * t;
    if (p0 >= P) return;

    const float fres = (float)RES;
    const float* __restrict__ xp = x + (size_t)p0 * 3;
    // non-temporal: x is single-use stream, keep it out of L2
    const float ax = __builtin_nontemporal_load(xp + 0);
    const float ay = __builtin_nontemporal_load(xp + 1);
    const float az = __builtin_nontemporal_load(xp + 2);
    const float bx = __builtin_nontemporal_load(xp + 3);
    const float by = __builtin_nontemporal_load(xp + 4);
    const float bz = __builtin_nontemporal_load(xp + 5);

    Prep A, B;
    prep_point(ax, ay, az, fres, A);
    prep_point(bx, by, bz, fres, B);

    const float2* __restrict__ tbl =
        reinterpret_cast<const float2*>(hashmap) + (size_t)LVL * (size_t)kT;

    // 16 gathers issued as one cluster (normal/cached: table must live in L2)
    float2 fa[8], fb[8];
#pragma unroll
    for (int c = 0; c < 8; ++c) fa[c] = tbl[A.idx[c]];
#pragma unroll
    for (int c = 0; c < 8; ++c) fb[c] = tbl[B.idx[c]];

    float a0 = 0.0f, a1 = 0.0f, b0 = 0.0f, b1 = 0.0f;
#pragma unroll
    for (int c = 0; c < 8; ++c) {
        a0 = fmaf(A.w[c], fa[c].x, a0);
        a1 = fmaf(A.w[c], fa[c].y, a1);
        b0 = fmaf(B.w[c], fb[c].x, b0);
        b1 = fmaf(B.w[c], fb[c].y, b1);
    }

    float2* dst = ws2 + (size_t)LVL * (size_t)P + (size_t)p0;
    if (p0 + 1 < P) {
        // p0 even -> 16B aligned store; nt: single-use stream
        vfloat4 v = {a0, a1, b0, b1};
        __builtin_nontemporal_store(v, reinterpret_cast<vfloat4*>(dst));
    } else {
        vfloat2 v = {a0, a1};
        __builtin_nontemporal_store(v, reinterpret_cast<vfloat2*>(dst));
    }
}

// ---------------------------------------------------------------------------
// ws[l][p] float2 -> out[p][32] f32, LDS-staged so BOTH sides are
// perfectly lane-coalesced. LDS [256][17] float2: pad 17 -> 2-way bank
// aliasing (free per m136).
// ---------------------------------------------------------------------------
__global__ __launch_bounds__(256) void hashgrid_transpose(
    const float2* __restrict__ ws2,      // [kL][P]
    float4* __restrict__ out4,           // [P*8]
    int P)
{
    __shared__ float2 lds[256 * 17];
    const int tid = threadIdx.x;
    const int base = blockIdx.x * 256;

    // read phase: for each level, 256 consecutive float2 (2KB) -> LDS
#pragma unroll
    for (int l = 0; l < kL; ++l) {
        const int p = base + tid;
        float2 v = (p < P) ? ws2[(size_t)l * (size_t)P + (size_t)p]
                           : make_float2(0.0f, 0.0f);
        lds[tid * 17 + l] = v;
    }
    __syncthreads();

    // write phase: 2048 float4 for this block's 256 points,
    // consecutive lanes -> consecutive 16B -> perfect coalescing.
    const int nvec = min(P - base, 256) * 8;
#pragma unroll
    for (int j = 0; j < 8; ++j) {
        const int tvec = j * 256 + tid;          // 0..2047
        if (tvec < nvec) {
            const int pl = tvec >> 3;            // local point
            const int m = tvec & 7;              // which float4 of the row
            const float2 a = lds[pl * 17 + 2 * m];
            const float2 b = lds[pl * 17 + 2 * m + 1];
            out4[(size_t)base * 8 + (size_t)tvec] = make_float4(a.x, a.y, b.x, b.y);
        }
    }
}

// ---------------------------------------------------------------------------
// Fallback (round-6 monolithic): used only if ws_size can't hold [L][P]f2.
// ---------------------------------------------------------------------------
__global__ __launch_bounds__(256) void hashgrid_fwd_mono(
    const float* __restrict__ x,
    const float* __restrict__ hashmap,
    float4* __restrict__ out4,
    int P)
{
    constexpr int RES[16] = {16, 20, 25, 32, 40, 50, 64, 80,
                             101, 128, 161, 203, 256, 322, 406, 512};
    const int p = blockIdx.x * 256 + threadIdx.x;
    if (p >= P) return;
    const float px = x[p * 3 + 0];
    const float py = x[p * 3 + 1];
    const float pz = x[p * 3 + 2];
    float acc[32];
#pragma unroll
    for (int l = 0; l < kL; ++l) {
        Prep pr;
        prep_point(px, py, pz, (float)RES[l], pr);
        const float2* __restrict__ tbl =
            reinterpret_cast<const float2*>(hashmap) + (size_t)l * (size_t)kT;
        float2 f[8];
#pragma unroll
        for (int c = 0; c < 8; ++c) f[c] = tbl[pr.idx[c]];
        float a0 = 0.0f, a1 = 0.0f;
#pragma unroll
        for (int c = 0; c < 8; ++c) {
            a0 = fmaf(pr.w[c], f[c].x, a0);
            a1 = fmaf(pr.w[c], f[c].y, a1);
        }
        acc[2 * l + 0] = a0;
        acc[2 * l + 1] = a1;
    }
    float4* __restrict__ dst = out4 + (size_t)p * 8;
#pragma unroll
    for (int j = 0; j < 8; ++j) {
        dst[j] = make_float4(acc[4 * j + 0], acc[4 * j + 1],
                             acc[4 * j + 2], acc[4 * j + 3]);
    }
}

extern "C" void kernel_launch(void* const* d_in, const int* in_sizes, int n_in,
                              void* d_out, int out_size, void* d_ws, size_t ws_size,
                              hipStream_t stream) {
    const float* x = (const float*)d_in[0];        // [P,3] f32
    const float* hashmap = (const float*)d_in[1];  // [L,T,F] f32
    float4* out4 = (float4*)d_out;                 // [P,32] f32 as float4

    const int P = in_sizes[0] / 3;
    const int block = 256;
    const int grid_p = (P + block - 1) / block;            // per-point grids
    const int grid_h = ((P + 1) / 2 + block - 1) / block;  // 2 points/thread

    const size_t ws_needed = (size_t)kL * (size_t)P * sizeof(float2);
    if (ws_size < ws_needed) {
        hashgrid_fwd_mono<<<grid_p, block, 0, stream>>>(x, hashmap, out4, P);
        return;
    }

    float2* ws2 = (float2*)d_ws;

#define LAUNCH_LEVEL(R, L) \
    hashgrid_level2<R, L><<<grid_h, block, 0, stream>>>(x, hashmap, ws2, P)

    LAUNCH_LEVEL(16, 0);
    LAUNCH_LEVEL(20, 1);
    LAUNCH_LEVEL(25, 2);
    LAUNCH_LEVEL(32, 3);
    LAUNCH_LEVEL(40, 4);
    LAUNCH_LEVEL(50, 5);
    LAUNCH_LEVEL(64, 6);
    LAUNCH_LEVEL(80, 7);
    LAUNCH_LEVEL(101, 8);
    LAUNCH_LEVEL(128, 9);
    LAUNCH_LEVEL(161, 10);
    LAUNCH_LEVEL(203, 11);
    LAUNCH_LEVEL(256, 12);
    LAUNCH_LEVEL(322, 13);
    LAUNCH_LEVEL(406, 14);
    LAUNCH_LEVEL(512, 15);
#undef LAUNCH_LEVEL

    hashgrid_transpose<<<grid_p, block, 0, stream>>>(ws2, out4, P);
}

// Round 11
// 1092.553 us; speedup vs baseline: 1.1375x; 1.1375x over previous
//
#include <hip/hip_runtime.h>
#include <cstdint>
#include <cstddef>

namespace {
constexpr int kL = 16;                    // levels
constexpr uint32_t kT = 1u << 19;         // hash table entries per level
constexpr uint32_t kTmask = kT - 1u;
constexpr uint32_t kP1 = 2654435761u;     // spatial hash primes
constexpr uint32_t kP2 = 805459861u;

// native clang vectors: __builtin_nontemporal_* requires these
typedef float vfloat4 __attribute__((ext_vector_type(4)));
typedef float vfloat2 __attribute__((ext_vector_type(2)));
}

// Per-point prep: everything except the gathers (indices + weights).
struct Prep {
    uint32_t idx[8];
    float w[8];
};

__device__ __forceinline__ void prep_point(float px, float py, float pz,
                                           float fres, Prep& pr) {
    // scale, floor, frac (fp32 ops match the reference exactly)
    const float xs0 = px * fres;
    const float xs1 = py * fres;
    const float xs2 = pz * fres;
    const float fl0 = floorf(xs0);
    const float fl1 = floorf(xs1);
    const float fl2 = floorf(xs2);
    const float fx = xs0 - fl0;
    const float fy = xs1 - fl1;
    const float fz = xs2 - fl2;
    const uint32_t i0 = (uint32_t)(int)fl0;
    const uint32_t i1 = (uint32_t)(int)fl1;
    const uint32_t i2 = (uint32_t)(int)fl2;

    // factored hash: h(c0,c1,c2) = c0 ^ c1*P1 ^ c2*P2 (uint32 wrap)
    const uint32_t h0a = i0;
    const uint32_t h0b = i0 + 1u;
    const uint32_t h1a = i1 * kP1;
    const uint32_t h1b = (i1 + 1u) * kP1;
    const uint32_t h2a = i2 * kP2;
    const uint32_t h2b = (i2 + 1u) * kP2;

    pr.idx[0] = (h0a ^ h1a ^ h2a) & kTmask;
    pr.idx[1] = (h0a ^ h1a ^ h2b) & kTmask;
    pr.idx[2] = (h0a ^ h1b ^ h2a) & kTmask;
    pr.idx[3] = (h0a ^ h1b ^ h2b) & kTmask;
    pr.idx[4] = (h0b ^ h1a ^ h2a) & kTmask;
    pr.idx[5] = (h0b ^ h1a ^ h2b) & kTmask;
    pr.idx[6] = (h0b ^ h1b ^ h2a) & kTmask;
    pr.idx[7] = (h0b ^ h1b ^ h2b) & kTmask;

    const float wx0 = 1.0f - fx, wx1 = fx;
    const float wy0 = 1.0f - fy, wy1 = fy;
    const float wz0 = 1.0f - fz, wz1 = fz;
    pr.w[0] = wx0 * wy0 * wz0;
    pr.w[1] = wx0 * wy0 * wz1;
    pr.w[2] = wx0 * wy1 * wz0;
    pr.w[3] = wx0 * wy1 * wz1;
    pr.w[4] = wx1 * wy0 * wz0;
    pr.w[5] = wx1 * wy0 * wz1;
    pr.w[6] = wx1 * wy1 * wz0;
    pr.w[7] = wx1 * wy1 * wz1;
}

__device__ __forceinline__ uint32_t f32_to_bf16_rne(float f) {
    const uint32_t u = __float_as_uint(f);
    return (u + 0x7fffu + ((u >> 16) & 1u)) >> 16;
}

// ---------------------------------------------------------------------------
// Pre-pass: hashmap [L,T,F] f32 -> packed 2xbf16 per entry (4B) in ws.
// Each level's table shrinks 4MB -> 2MB so it fits the 4MB per-XCD L2
// WITH slack (theory: the 4MB fp32 table had zero L2 capacity margin ->
// random-gather misses to HBM kept fine levels at ~3-4x their TA floor).
// 2 entries per thread: float4 read, uint2 write, fully coalesced.
// ---------------------------------------------------------------------------
__global__ __launch_bounds__(256) void convert_tables(
    const float4* __restrict__ hm4,      // [L*T/2] (pairs of float2 entries)
    uint2* __restrict__ tbl_bf,          // [L*T/2] (pairs of packed entries)
    int npairs)
{
    const int i = blockIdx.x * 256 + threadIdx.x;
    if (i >= npairs) return;
    const float4 v = hm4[i];
    uint2 o;
    o.x = (f32_to_bf16_rne(v.y) << 16) | f32_to_bf16_rne(v.x);
    o.y = (f32_to_bf16_rne(v.w) << 16) | f32_to_bf16_rne(v.z);
    tbl_bf[i] = o;
}

// ---------------------------------------------------------------------------
// Level-major pass, 2 points per thread, bf16-packed table.
// GPU-wide working set = ONE 2MB table -> L2-resident with slack.
// Streams (x, ws2) stay non-temporal (neutral in r10, mechanism-harmless).
// unpack: f0 = asfloat(u<<16), f1 = asfloat(u & 0xffff0000).
// ---------------------------------------------------------------------------
template <int RES, int LVL>
__global__ __launch_bounds__(256) void hashgrid_level2(
    const float* __restrict__ x,         // [P,3]
    const uint32_t* __restrict__ tbl_bf, // [kL][kT] packed 2xbf16
    float2* __restrict__ ws2,            // [kL][P] float2
    int P)
{
    const int t = blockIdx.x * 256 + threadIdx.x;
    const int p0 = 2 * t;
    if (p0 >= P) return;

    const float fres = (float)RES;
    const float* __restrict__ xp = x + (size_t)p0 * 3;
    const float ax = __builtin_nontemporal_load(xp + 0);
    const float ay = __builtin_nontemporal_load(xp + 1);
    const float az = __builtin_nontemporal_load(xp + 2);
    const float bx = __builtin_nontemporal_load(xp + 3);
    const float by = __builtin_nontemporal_load(xp + 4);
    const float bz = __builtin_nontemporal_load(xp + 5);

    Prep A, B;
    prep_point(ax, ay, az, fres, A);
    prep_point(bx, by, bz, fres, B);

    const uint32_t* __restrict__ tbl = tbl_bf + (size_t)LVL * (size_t)kT;

    // 16 gathers issued as one cluster (cached: table must live in L2)
    uint32_t ua[8], ub[8];
#pragma unroll
    for (int c = 0; c < 8; ++c) ua[c] = tbl[A.idx[c]];
#pragma unroll
    for (int c = 0; c < 8; ++c) ub[c] = tbl[B.idx[c]];

    float a0 = 0.0f, a1 = 0.0f, b0 = 0.0f, b1 = 0.0f;
#pragma unroll
    for (int c = 0; c < 8; ++c) {
        a0 = fmaf(A.w[c], __uint_as_float(ua[c] << 16), a0);
        a1 = fmaf(A.w[c], __uint_as_float(ua[c] & 0xffff0000u), a1);
        b0 = fmaf(B.w[c], __uint_as_float(ub[c] << 16), b0);
        b1 = fmaf(B.w[c], __uint_as_float(ub[c] & 0xffff0000u), b1);
    }

    float2* dst = ws2 + (size_t)LVL * (size_t)P + (size_t)p0;
    if (p0 + 1 < P) {
        vfloat4 v = {a0, a1, b0, b1};
        __builtin_nontemporal_store(v, reinterpret_cast<vfloat4*>(dst));
    } else {
        vfloat2 v = {a0, a1};
        __builtin_nontemporal_store(v, reinterpret_cast<vfloat2*>(dst));
    }
}

// ---------------------------------------------------------------------------
// ws[l][p] float2 -> out[p][32] f32, LDS-staged so BOTH sides are
// perfectly lane-coalesced. LDS [256][17] float2: pad 17 -> 2-way bank
// aliasing (free per m136).
// ---------------------------------------------------------------------------
__global__ __launch_bounds__(256) void hashgrid_transpose(
    const float2* __restrict__ ws2,      // [kL][P]
    float4* __restrict__ out4,           // [P*8]
    int P)
{
    __shared__ float2 lds[256 * 17];
    const int tid = threadIdx.x;
    const int base = blockIdx.x * 256;

#pragma unroll
    for (int l = 0; l < kL; ++l) {
        const int p = base + tid;
        float2 v = (p < P) ? ws2[(size_t)l * (size_t)P + (size_t)p]
                           : make_float2(0.0f, 0.0f);
        lds[tid * 17 + l] = v;
    }
    __syncthreads();

    const int nvec = min(P - base, 256) * 8;
#pragma unroll
    for (int j = 0; j < 8; ++j) {
        const int tvec = j * 256 + tid;          // 0..2047
        if (tvec < nvec) {
            const int pl = tvec >> 3;            // local point
            const int m = tvec & 7;              // which float4 of the row
            const float2 a = lds[pl * 17 + 2 * m];
            const float2 b = lds[pl * 17 + 2 * m + 1];
            out4[(size_t)base * 8 + (size_t)tvec] = make_float4(a.x, a.y, b.x, b.y);
        }
    }
}

// ---------------------------------------------------------------------------
// Fallback (monolithic, fp32 table): used only if ws too small.
// ---------------------------------------------------------------------------
__global__ __launch_bounds__(256) void hashgrid_fwd_mono(
    const float* __restrict__ x,
    const float* __restrict__ hashmap,
    float4* __restrict__ out4,
    int P)
{
    constexpr int RES[16] = {16, 20, 25, 32, 40, 50, 64, 80,
                             101, 128, 161, 203, 256, 322, 406, 512};
    const int p = blockIdx.x * 256 + threadIdx.x;
    if (p >= P) return;
    const float px = x[p * 3 + 0];
    const float py = x[p * 3 + 1];
    const float pz = x[p * 3 + 2];
    float acc[32];
#pragma unroll
    for (int l = 0; l < kL; ++l) {
        Prep pr;
        prep_point(px, py, pz, (float)RES[l], pr);
        const float2* __restrict__ tbl =
            reinterpret_cast<const float2*>(hashmap) + (size_t)l * (size_t)kT;
        float2 f[8];
#pragma unroll
        for (int c = 0; c < 8; ++c) f[c] = tbl[pr.idx[c]];
        float a0 = 0.0f, a1 = 0.0f;
#pragma unroll
        for (int c = 0; c < 8; ++c) {
            a0 = fmaf(pr.w[c], f[c].x, a0);
            a1 = fmaf(pr.w[c], f[c].y, a1);
        }
        acc[2 * l + 0] = a0;
        acc[2 * l + 1] = a1;
    }
    float4* __restrict__ dst = out4 + (size_t)p * 8;
#pragma unroll
    for (int j = 0; j < 8; ++j) {
        dst[j] = make_float4(acc[4 * j + 0], acc[4 * j + 1],
                             acc[4 * j + 2], acc[4 * j + 3]);
    }
}

extern "C" void kernel_launch(void* const* d_in, const int* in_sizes, int n_in,
                              void* d_out, int out_size, void* d_ws, size_t ws_size,
                              hipStream_t stream) {
    const float* x = (const float*)d_in[0];        // [P,3] f32
    const float* hashmap = (const float*)d_in[1];  // [L,T,F] f32
    float4* out4 = (float4*)d_out;                 // [P,32] f32 as float4

    const int P = in_sizes[0] / 3;
    const int block = 256;
    const int grid_p = (P + block - 1) / block;            // per-point grids
    const int grid_h = ((P + 1) / 2 + block - 1) / block;  // 2 points/thread

    // ws layout: [0, 32MB) bf16 tables; [32MB, 32MB+256MB) level outputs
    const size_t tbl_bytes = (size_t)kL * (size_t)kT * 4u;             // 32 MB
    const size_t ws2_bytes = (size_t)kL * (size_t)P * sizeof(float2);  // 256 MB
    if (ws_size < tbl_bytes + ws2_bytes) {
        hashgrid_fwd_mono<<<grid_p, block, 0, stream>>>(x, hashmap, out4, P);
        return;
    }

    uint32_t* tbl_bf = (uint32_t*)d_ws;
    float2* ws2 = (float2*)((char*)d_ws + tbl_bytes);

    // pre-pass: fp32 table -> packed bf16 (96 MB streaming, ~15us)
    const int npairs = (int)((size_t)kL * (size_t)kT / 2);
    convert_tables<<<(npairs + block - 1) / block, block, 0, stream>>>(
        (const float4*)hashmap, (uint2*)tbl_bf, npairs);

#define LAUNCH_LEVEL(R, L) \
    hashgrid_level2<R, L><<<grid_h, block, 0, stream>>>(x, tbl_bf, ws2, P)

    LAUNCH_LEVEL(16, 0);
    LAUNCH_LEVEL(20, 1);
    LAUNCH_LEVEL(25, 2);
    LAUNCH_LEVEL(32, 3);
    LAUNCH_LEVEL(40, 4);
    LAUNCH_LEVEL(50, 5);
    LAUNCH_LEVEL(64, 6);
    LAUNCH_LEVEL(80, 7);
    LAUNCH_LEVEL(101, 8);
    LAUNCH_LEVEL(128, 9);
    LAUNCH_LEVEL(161, 10);
    LAUNCH_LEVEL(203, 11);
    LAUNCH_LEVEL(256, 12);
    LAUNCH_LEVEL(322, 13);
    LAUNCH_LEVEL(406, 14);
    LAUNCH_LEVEL(512, 15);
#undef LAUNCH_LEVEL

    hashgrid_transpose<<<grid_p, block, 0, stream>>>(ws2, out4, P);
}

// Round 12
// 975.552 us; speedup vs baseline: 1.2740x; 1.1199x over previous
//
#include <hip/hip_runtime.h>
#include <cstdint>
#include <cstddef>

namespace {
constexpr int kL = 16;                    // levels
constexpr uint32_t kT = 1u << 19;         // hash table entries per level
constexpr uint32_t kTmask = kT - 1u;
constexpr uint32_t kP1 = 2654435761u;     // spatial hash primes
constexpr uint32_t kP2 = 805459861u;
}

// Per-point prep: everything except the gathers (indices + weights).
struct Prep {
    uint32_t idx[8];
    float w[8];
};

__device__ __forceinline__ void prep_point(float px, float py, float pz,
                                           float fres, Prep& pr) {
    // scale, floor, frac (fp32 ops match the reference exactly)
    const float xs0 = px * fres;
    const float xs1 = py * fres;
    const float xs2 = pz * fres;
    const float fl0 = floorf(xs0);
    const float fl1 = floorf(xs1);
    const float fl2 = floorf(xs2);
    const float fx = xs0 - fl0;
    const float fy = xs1 - fl1;
    const float fz = xs2 - fl2;
    const uint32_t i0 = (uint32_t)(int)fl0;
    const uint32_t i1 = (uint32_t)(int)fl1;
    const uint32_t i2 = (uint32_t)(int)fl2;

    // factored hash: h(c0,c1,c2) = c0 ^ c1*P1 ^ c2*P2 (uint32 wrap)
    const uint32_t h0a = i0;
    const uint32_t h0b = i0 + 1u;
    const uint32_t h1a = i1 * kP1;
    const uint32_t h1b = (i1 + 1u) * kP1;
    const uint32_t h2a = i2 * kP2;
    const uint32_t h2b = (i2 + 1u) * kP2;

    pr.idx[0] = (h0a ^ h1a ^ h2a) & kTmask;
    pr.idx[1] = (h0a ^ h1a ^ h2b) & kTmask;
    pr.idx[2] = (h0a ^ h1b ^ h2a) & kTmask;
    pr.idx[3] = (h0a ^ h1b ^ h2b) & kTmask;
    pr.idx[4] = (h0b ^ h1a ^ h2a) & kTmask;
    pr.idx[5] = (h0b ^ h1a ^ h2b) & kTmask;
    pr.idx[6] = (h0b ^ h1b ^ h2a) & kTmask;
    pr.idx[7] = (h0b ^ h1b ^ h2b) & kTmask;

    const float wx0 = 1.0f - fx, wx1 = fx;
    const float wy0 = 1.0f - fy, wy1 = fy;
    const float wz0 = 1.0f - fz, wz1 = fz;
    pr.w[0] = wx0 * wy0 * wz0;
    pr.w[1] = wx0 * wy0 * wz1;
    pr.w[2] = wx0 * wy1 * wz0;
    pr.w[3] = wx0 * wy1 * wz1;
    pr.w[4] = wx1 * wy0 * wz0;
    pr.w[5] = wx1 * wy0 * wz1;
    pr.w[6] = wx1 * wy1 * wz0;
    pr.w[7] = wx1 * wy1 * wz1;
}

__device__ __forceinline__ uint32_t f32_to_bf16_rne(float f) {
    const uint32_t u = __float_as_uint(f);
    return (u + 0x7fffu + ((u >> 16) & 1u)) >> 16;
}

// ---------------------------------------------------------------------------
// Pre-pass: hashmap [L,T,F] f32 -> packed 2xbf16 per entry (4B) in ws.
// Table per level: 2MB -> L2-resident with slack.
// ---------------------------------------------------------------------------
__global__ __launch_bounds__(256) void convert_tables(
    const float4* __restrict__ hm4,      // [L*T/2] (pairs of float2 entries)
    uint2* __restrict__ tbl_bf,          // [L*T/2] (pairs of packed entries)
    int npairs)
{
    const int i = blockIdx.x * 256 + threadIdx.x;
    if (i >= npairs) return;
    const float4 v = hm4[i];
    uint2 o;
    o.x = (f32_to_bf16_rne(v.y) << 16) | f32_to_bf16_rne(v.x);
    o.y = (f32_to_bf16_rne(v.w) << 16) | f32_to_bf16_rne(v.z);
    tbl_bf[i] = o;
}

// ---------------------------------------------------------------------------
// MEGA level-major pass: ONE dispatch, grid = kL * blocksPerLevel.
// Block's level = blockIdx.x / blocksPerLevel. HW dispatches blocks in
// ascending order and only ~1 level's worth of blocks is resident at a
// time -> moving window of <=2 levels (4MB bf16) live GPU-wide, AND
// level l+1's heads fill CUs while level l's tails drain (removes 15
// full dispatch-drain barriers vs the per-level-kernel version).
// 2 points/thread; ws output packed bf16 (halves ws traffic).
// ---------------------------------------------------------------------------
__global__ __launch_bounds__(256) void hashgrid_levels(
    const float* __restrict__ x,         // [P,3]
    const uint32_t* __restrict__ tbl_bf, // [kL][kT] packed 2xbf16
    uint32_t* __restrict__ wsb,          // [kL][P] packed 2xbf16 results
    int P, int blocksPerLevel)
{
    const int l = blockIdx.x / blocksPerLevel;            // wave-uniform
    const int b = blockIdx.x - l * blocksPerLevel;
    const int t = b * 256 + threadIdx.x;
    const int p0 = 2 * t;
    if (p0 >= P) return;

    // res = int(16 * 2^(l/3)) computed branch-arithmetically (exact; r1-verified)
    const int oct = (l * 11) >> 5;        // == l/3 for l in [0,15]
    const int rem = l - 3 * oct;
    const float base = (float)(16 << oct);
    const float cmul = (rem == 0) ? 1.0f : ((rem == 1) ? 1.2599210499f : 1.5874010520f);
    const float fres = (float)(int)(base * cmul);

    const float* __restrict__ xp = x + (size_t)p0 * 3;
    const float ax = xp[0], ay = xp[1], az = xp[2];
    const float bx = xp[3], by = xp[4], bz = xp[5];

    Prep A, B;
    prep_point(ax, ay, az, fres, A);
    prep_point(bx, by, bz, fres, B);

    const uint32_t* __restrict__ tbl = tbl_bf + (size_t)l * (size_t)kT;

    // 16 gathers issued as one cluster (cached: table lives in L2)
    uint32_t ua[8], ub[8];
#pragma unroll
    for (int c = 0; c < 8; ++c) ua[c] = tbl[A.idx[c]];
#pragma unroll
    for (int c = 0; c < 8; ++c) ub[c] = tbl[B.idx[c]];

    float a0 = 0.0f, a1 = 0.0f, b0 = 0.0f, b1 = 0.0f;
#pragma unroll
    for (int c = 0; c < 8; ++c) {
        a0 = fmaf(A.w[c], __uint_as_float(ua[c] << 16), a0);
        a1 = fmaf(A.w[c], __uint_as_float(ua[c] & 0xffff0000u), a1);
        b0 = fmaf(B.w[c], __uint_as_float(ub[c] << 16), b0);
        b1 = fmaf(B.w[c], __uint_as_float(ub[c] & 0xffff0000u), b1);
    }

    // pack results to bf16x2 per point (ws traffic halved vs f32)
    const uint32_t pa = (f32_to_bf16_rne(a1) << 16) | f32_to_bf16_rne(a0);
    const uint32_t pb = (f32_to_bf16_rne(b1) << 16) | f32_to_bf16_rne(b0);

    uint32_t* dst = wsb + (size_t)l * (size_t)P + (size_t)p0;
    if (p0 + 1 < P) {
        *reinterpret_cast<uint2*>(dst) = make_uint2(pa, pb);  // 8B aligned
    } else {
        *dst = pa;
    }
}

// ---------------------------------------------------------------------------
// wsb[l][p] bf16x2 -> out[p][32] f32, LDS-staged so BOTH sides are
// lane-coalesced. LDS [256][17] uint: stride 17 words -> 2-way bank
// aliasing on the read phase (free per m136).
// ---------------------------------------------------------------------------
__global__ __launch_bounds__(256) void hashgrid_transpose(
    const uint32_t* __restrict__ wsb,    // [kL][P]
    float4* __restrict__ out4,           // [P*8]
    int P)
{
    __shared__ uint32_t lds[256 * 17];
    const int tid = threadIdx.x;
    const int base = blockIdx.x * 256;

    // read phase: per level, 256 consecutive uints (1KB) -> LDS
#pragma unroll
    for (int l = 0; l < kL; ++l) {
        const int p = base + tid;
        const uint32_t v = (p < P) ? wsb[(size_t)l * (size_t)P + (size_t)p] : 0u;
        lds[tid * 17 + l] = v;
    }
    __syncthreads();

    // write phase: 2048 float4 (= 256 rows x 128B), lanes contiguous.
    const int nvec = min(P - base, 256) * 8;
#pragma unroll
    for (int j = 0; j < 8; ++j) {
        const int tvec = j * 256 + tid;          // 0..2047
        if (tvec < nvec) {
            const int pl = tvec >> 3;            // local point
            const int m = tvec & 7;              // which float4 of the row
            const uint32_t ua = lds[pl * 17 + 2 * m];      // levels 2m
            const uint32_t ub = lds[pl * 17 + 2 * m + 1];  // level 2m+1
            out4[(size_t)base * 8 + (size_t)tvec] =
                make_float4(__uint_as_float(ua << 16),
                            __uint_as_float(ua & 0xffff0000u),
                            __uint_as_float(ub << 16),
                            __uint_as_float(ub & 0xffff0000u));
        }
    }
}

// ---------------------------------------------------------------------------
// Fallback (monolithic, fp32 table): used only if ws too small.
// ---------------------------------------------------------------------------
__global__ __launch_bounds__(256) void hashgrid_fwd_mono(
    const float* __restrict__ x,
    const float* __restrict__ hashmap,
    float4* __restrict__ out4,
    int P)
{
    constexpr int RES[16] = {16, 20, 25, 32, 40, 50, 64, 80,
                             101, 128, 161, 203, 256, 322, 406, 512};
    const int p = blockIdx.x * 256 + threadIdx.x;
    if (p >= P) return;
    const float px = x[p * 3 + 0];
    const float py = x[p * 3 + 1];
    const float pz = x[p * 3 + 2];
    float acc[32];
#pragma unroll
    for (int l = 0; l < kL; ++l) {
        Prep pr;
        prep_point(px, py, pz, (float)RES[l], pr);
        const float2* __restrict__ tbl =
            reinterpret_cast<const float2*>(hashmap) + (size_t)l * (size_t)kT;
        float2 f[8];
#pragma unroll
        for (int c = 0; c < 8; ++c) f[c] = tbl[pr.idx[c]];
        float a0 = 0.0f, a1 = 0.0f;
#pragma unroll
        for (int c = 0; c < 8; ++c) {
            a0 = fmaf(pr.w[c], f[c].x, a0);
            a1 = fmaf(pr.w[c], f[c].y, a1);
        }
        acc[2 * l + 0] = a0;
        acc[2 * l + 1] = a1;
    }
    float4* __restrict__ dst = out4 + (size_t)p * 8;
#pragma unroll
    for (int j = 0; j < 8; ++j) {
        dst[j] = make_float4(acc[4 * j + 0], acc[4 * j + 1],
                             acc[4 * j + 2], acc[4 * j + 3]);
    }
}

extern "C" void kernel_launch(void* const* d_in, const int* in_sizes, int n_in,
                              void* d_out, int out_size, void* d_ws, size_t ws_size,
                              hipStream_t stream) {
    const float* x = (const float*)d_in[0];        // [P,3] f32
    const float* hashmap = (const float*)d_in[1];  // [L,T,F] f32
    float4* out4 = (float4*)d_out;                 // [P,32] f32 as float4

    const int P = in_sizes[0] / 3;
    const int block = 256;
    const int grid_p = (P + block - 1) / block;    // per-point grid

    // ws layout: [0, 32MB) bf16 tables; then [kL][P] bf16x2 results (64MB)
    const size_t tbl_bytes = (size_t)kL * (size_t)kT * 4u;               // 32 MB
    const size_t wsb_bytes = (size_t)kL * (size_t)P * sizeof(uint32_t);  // 128 MB
    if (ws_size < tbl_bytes + wsb_bytes) {
        hashgrid_fwd_mono<<<grid_p, block, 0, stream>>>(x, hashmap, out4, P);
        return;
    }

    uint32_t* tbl_bf = (uint32_t*)d_ws;
    uint32_t* wsb = (uint32_t*)((char*)d_ws + tbl_bytes);

    // pre-pass: fp32 table -> packed bf16 (96 MB streaming)
    const int npairs = (int)((size_t)kL * (size_t)kT / 2);
    convert_tables<<<(npairs + block - 1) / block, block, 0, stream>>>(
        (const float4*)hashmap, (uint2*)tbl_bf, npairs);

    // mega level-major dispatch: 2 points/thread
    const int blocksPerLevel = ((P + 1) / 2 + block - 1) / block;
    hashgrid_levels<<<kL * blocksPerLevel, block, 0, stream>>>(
        x, tbl_bf, wsb, P, blocksPerLevel);

    hashgrid_transpose<<<grid_p, block, 0, stream>>>(wsb, out4, P);
}

// Round 13
// 881.281 us; speedup vs baseline: 1.4102x; 1.1070x over previous
//
#include <hip/hip_runtime.h>
#include <cstdint>
#include <cstddef>

namespace {
constexpr int kL = 16;                    // levels
constexpr uint32_t kT = 1u << 19;         // hash table entries per level
constexpr uint32_t kTmask = kT - 1u;
constexpr uint32_t kP1 = 2654435761u;     // spatial hash primes
constexpr uint32_t kP2 = 805459861u;

constexpr int kRES[16] = {16, 20, 25, 32, 40, 50, 64, 80,
                          101, 128, 161, 203, 256, 322, 406, 512};

// level modes
constexpr int MODE_HASH = 0;   // random hash gather (levels 8-15)
constexpr int MODE_DENSE1 = 1; // dense grid, 4B entries (level 7)
constexpr int MODE_DENSE2 = 2; // dense grid, z-paired 8B entries (levels 0-6)
}

__device__ __forceinline__ uint32_t hash3(uint32_t c0, uint32_t c1, uint32_t c2) {
    return (c0 ^ (c1 * kP1) ^ (c2 * kP2)) & kTmask;
}

__device__ __forceinline__ uint32_t f32_to_bf16_rne(float f) {
    const uint32_t u = __float_as_uint(f);
    return (u + 0x7fffu + ((u >> 16) & 1u)) >> 16;
}

// unpack packed bf16x2: low half = feature0, high = feature1
__device__ __forceinline__ float bfx(uint32_t u) { return __uint_as_float(u << 16); }
__device__ __forceinline__ float bfy(uint32_t u) { return __uint_as_float(u & 0xffff0000u); }

// ---------------------------------------------------------------------------
// Pre-pass 1: hashmap [L,T,F] f32 -> packed 2xbf16 per entry (4B).
// ---------------------------------------------------------------------------
__global__ __launch_bounds__(256) void convert_tables(
    const float4* __restrict__ hm4, uint2* __restrict__ tbl_bf, int npairs)
{
    const int i = blockIdx.x * 256 + threadIdx.x;
    if (i >= npairs) return;
    const float4 v = hm4[i];
    uint2 o;
    o.x = (f32_to_bf16_rne(v.y) << 16) | f32_to_bf16_rne(v.x);
    o.y = (f32_to_bf16_rne(v.w) << 16) | f32_to_bf16_rne(v.z);
    tbl_bf[i] = o;
}

// ---------------------------------------------------------------------------
// Pre-pass 2a: dense z-paired table for one coarse level.
// slot(c0,c1,c2) = (c0*(R+1)+c1)*R + c2, c0,c1 in [0,R], c2 in [0,R-1].
// value = (tbl[h(c0,c1,c2)], tbl[h(c0,c1,c2+1)]) -- collision semantics of
// the reference are preserved exactly (we copy the hashed VALUE per corner).
// ---------------------------------------------------------------------------
template <int R, int LVL>
__global__ __launch_bounds__(256) void build_dense2(
    const uint32_t* __restrict__ tbl_bf, uint2* __restrict__ d2)
{
    const int n = (R + 1) * (R + 1) * R;
    const int s = blockIdx.x * 256 + threadIdx.x;
    if (s >= n) return;
    const int c2 = s % R;
    const int t = s / R;
    const int c1 = t % (R + 1);
    const int c0 = t / (R + 1);
    const uint32_t* tbl = tbl_bf + (size_t)LVL * (size_t)kT;
    uint2 o;
    o.x = tbl[hash3((uint32_t)c0, (uint32_t)c1, (uint32_t)c2)];
    o.y = tbl[hash3((uint32_t)c0, (uint32_t)c1, (uint32_t)(c2 + 1))];
    d2[s] = o;
}

// Pre-pass 2b: dense 4B table (level 7, pair table would exceed L2).
template <int R, int LVL>
__global__ __launch_bounds__(256) void build_dense1(
    const uint32_t* __restrict__ tbl_bf, uint32_t* __restrict__ d1)
{
    const int n = (R + 1) * (R + 1) * (R + 1);
    const int s = blockIdx.x * 256 + threadIdx.x;
    if (s >= n) return;
    const int c2 = s % (R + 1);
    const int t = s / (R + 1);
    const int c1 = t % (R + 1);
    const int c0 = t / (R + 1);
    const uint32_t* tbl = tbl_bf + (size_t)LVL * (size_t)kT;
    d1[s] = tbl[hash3((uint32_t)c0, (uint32_t)c1, (uint32_t)c2)];
}

// ---------------------------------------------------------------------------
// per-level parameters for the mega kernel (kernarg, scalar-loaded)
// ---------------------------------------------------------------------------
struct Params16 {
    int mode[16];
    int res[16];
    float fres[16];
    unsigned long long off[16];   // byte offset of this level's table in ws
};

// ---------------------------------------------------------------------------
// MEGA level-major pass: ONE dispatch, grid = kL * blocksPerLevel; HW
// dispatches blocks in ascending order -> moving window of ~1 level live.
// Levels 0-6: DENSE2 (4x 8B spatially-local reads/point)
// Level  7  : DENSE1 (8x 4B spatially-local reads/point)
// Levels 8-15: HASH  (8x 4B random reads/point, table L2-resident)
// 2 points/thread; ws output packed bf16.
// ---------------------------------------------------------------------------
__global__ __launch_bounds__(256) void hashgrid_levels(
    const float* __restrict__ x,         // [P,3]
    const char* __restrict__ wsbase,     // ws base (tables live here)
    uint32_t* __restrict__ wsb,          // [kL][P] packed bf16x2 results
    int P, int blocksPerLevel, Params16 prm)
{
    const int l = blockIdx.x / blocksPerLevel;            // wave-uniform
    const int b = blockIdx.x - l * blocksPerLevel;
    const int t = b * 256 + threadIdx.x;
    const int p0 = 2 * t;
    if (p0 >= P) return;

    const int mode = prm.mode[l];
    const int R = prm.res[l];
    const float fres = prm.fres[l];
    const char* tblb = wsbase + prm.off[l];

    const float* __restrict__ xp = x + (size_t)p0 * 3;
    const float axx = xp[0], ayy = xp[1], azz = xp[2];
    const float bxx = xp[3], byy = xp[4], bzz = xp[5];

    float a0 = 0.0f, a1 = 0.0f, b0 = 0.0f, b1 = 0.0f;

    // per-point geometry (fp32 ops match the reference exactly)
#define GEOM(px, py, pz, i0, i1, i2, fx, fy, fz)                       \
    const float xs0 = (px) * fres, xs1 = (py) * fres, xs2 = (pz) * fres; \
    const float fl0 = floorf(xs0), fl1 = floorf(xs1), fl2 = floorf(xs2); \
    const float fx = xs0 - fl0, fy = xs1 - fl1, fz = xs2 - fl2;          \
    const int i0 = (int)fl0, i1 = (int)fl1, i2 = (int)fl2;

    if (mode == MODE_DENSE2) {
        const uint2* __restrict__ d2 = reinterpret_cast<const uint2*>(tblb);
        const int strideB = R;                 // +1 in c1
        const int strideA = R * (R + 1);       // +1 in c0
        {
            GEOM(axx, ayy, azz, i0, i1, i2, fx, fy, fz)
            const int base = (i0 * (R + 1) + i1) * R + i2;
            const uint2 u00 = d2[base];
            const uint2 u01 = d2[base + strideB];
            const uint2 u10 = d2[base + strideA];
            const uint2 u11 = d2[base + strideA + strideB];
            const float wx0 = 1.0f - fx, wx1 = fx;
            const float wy0 = 1.0f - fy, wy1 = fy;
            const float wz0 = 1.0f - fz, wz1 = fz;
            float wab;
            wab = wx0 * wy0;
            a0 = fmaf(wab * wz0, bfx(u00.x), a0); a1 = fmaf(wab * wz0, bfy(u00.x), a1);
            a0 = fmaf(wab * wz1, bfx(u00.y), a0); a1 = fmaf(wab * wz1, bfy(u00.y), a1);
            wab = wx0 * wy1;
            a0 = fmaf(wab * wz0, bfx(u01.x), a0); a1 = fmaf(wab * wz0, bfy(u01.x), a1);
            a0 = fmaf(wab * wz1, bfx(u01.y), a0); a1 = fmaf(wab * wz1, bfy(u01.y), a1);
            wab = wx1 * wy0;
            a0 = fmaf(wab * wz0, bfx(u10.x), a0); a1 = fmaf(wab * wz0, bfy(u10.x), a1);
            a0 = fmaf(wab * wz1, bfx(u10.y), a0); a1 = fmaf(wab * wz1, bfy(u10.y), a1);
            wab = wx1 * wy1;
            a0 = fmaf(wab * wz0, bfx(u11.x), a0); a1 = fmaf(wab * wz0, bfy(u11.x), a1);
            a0 = fmaf(wab * wz1, bfx(u11.y), a0); a1 = fmaf(wab * wz1, bfy(u11.y), a1);
        }
        {
            GEOM(bxx, byy, bzz, i0, i1, i2, fx, fy, fz)
            const int base = (i0 * (R + 1) + i1) * R + i2;
            const uint2 u00 = d2[base];
            const uint2 u01 = d2[base + strideB];
            const uint2 u10 = d2[base + strideA];
            const uint2 u11 = d2[base + strideA + strideB];
            const float wx0 = 1.0f - fx, wx1 = fx;
            const float wy0 = 1.0f - fy, wy1 = fy;
            const float wz0 = 1.0f - fz, wz1 = fz;
            float wab;
            wab = wx0 * wy0;
            b0 = fmaf(wab * wz0, bfx(u00.x), b0); b1 = fmaf(wab * wz0, bfy(u00.x), b1);
            b0 = fmaf(wab * wz1, bfx(u00.y), b0); b1 = fmaf(wab * wz1, bfy(u00.y), b1);
            wab = wx0 * wy1;
            b0 = fmaf(wab * wz0, bfx(u01.x), b0); b1 = fmaf(wab * wz0, bfy(u01.x), b1);
            b0 = fmaf(wab * wz1, bfx(u01.y), b0); b1 = fmaf(wab * wz1, bfy(u01.y), b1);
            wab = wx1 * wy0;
            b0 = fmaf(wab * wz0, bfx(u10.x), b0); b1 = fmaf(wab * wz0, bfy(u10.x), b1);
            b0 = fmaf(wab * wz1, bfx(u10.y), b0); b1 = fmaf(wab * wz1, bfy(u10.y), b1);
            wab = wx1 * wy1;
            b0 = fmaf(wab * wz0, bfx(u11.x), b0); b1 = fmaf(wab * wz0, bfy(u11.x), b1);
            b0 = fmaf(wab * wz1, bfx(u11.y), b0); b1 = fmaf(wab * wz1, bfy(u11.y), b1);
        }
    } else {
        // DENSE1 and HASH share structure: 8 uint gathers + weight fma
        const uint32_t* __restrict__ tbl = reinterpret_cast<const uint32_t*>(tblb);
        uint32_t ia[8], ib[8];
        float wa[8], wb[8];
        {
            GEOM(axx, ayy, azz, i0, i1, i2, fx, fy, fz)
            if (mode == MODE_DENSE1) {
                const int base = (i0 * (R + 1) + i1) * (R + 1) + i2;
                const int sB = R + 1, sA = (R + 1) * (R + 1);
                ia[0] = base;          ia[1] = base + 1;
                ia[2] = base + sB;     ia[3] = base + sB + 1;
                ia[4] = base + sA;     ia[5] = base + sA + 1;
                ia[6] = base + sA + sB; ia[7] = base + sA + sB + 1;
            } else {
                const uint32_t h0a = (uint32_t)i0, h0b = (uint32_t)i0 + 1u;
                const uint32_t h1a = (uint32_t)i1 * kP1, h1b = ((uint32_t)i1 + 1u) * kP1;
                const uint32_t h2a = (uint32_t)i2 * kP2, h2b = ((uint32_t)i2 + 1u) * kP2;
                ia[0] = (h0a ^ h1a ^ h2a) & kTmask; ia[1] = (h0a ^ h1a ^ h2b) & kTmask;
                ia[2] = (h0a ^ h1b ^ h2a) & kTmask; ia[3] = (h0a ^ h1b ^ h2b) & kTmask;
                ia[4] = (h0b ^ h1a ^ h2a) & kTmask; ia[5] = (h0b ^ h1a ^ h2b) & kTmask;
                ia[6] = (h0b ^ h1b ^ h2a) & kTmask; ia[7] = (h0b ^ h1b ^ h2b) & kTmask;
            }
            const float wx0 = 1.0f - fx, wx1 = fx;
            const float wy0 = 1.0f - fy, wy1 = fy;
            const float wz0 = 1.0f - fz, wz1 = fz;
            wa[0] = wx0 * wy0 * wz0; wa[1] = wx0 * wy0 * wz1;
            wa[2] = wx0 * wy1 * wz0; wa[3] = wx0 * wy1 * wz1;
            wa[4] = wx1 * wy0 * wz0; wa[5] = wx1 * wy0 * wz1;
            wa[6] = wx1 * wy1 * wz0; wa[7] = wx1 * wy1 * wz1;
        }
        {
            GEOM(bxx, byy, bzz, i0, i1, i2, fx, fy, fz)
            if (mode == MODE_DENSE1) {
                const int base = (i0 * (R + 1) + i1) * (R + 1) + i2;
                const int sB = R + 1, sA = (R + 1) * (R + 1);
                ib[0] = base;          ib[1] = base + 1;
                ib[2] = base + sB;     ib[3] = base + sB + 1;
                ib[4] = base + sA;     ib[5] = base + sA + 1;
                ib[6] = base + sA + sB; ib[7] = base + sA + sB + 1;
            } else {
                const uint32_t h0a = (uint32_t)i0, h0b = (uint32_t)i0 + 1u;
                const uint32_t h1a = (uint32_t)i1 * kP1, h1b = ((uint32_t)i1 + 1u) * kP1;
                const uint32_t h2a = (uint32_t)i2 * kP2, h2b = ((uint32_t)i2 + 1u) * kP2;
                ib[0] = (h0a ^ h1a ^ h2a) & kTmask; ib[1] = (h0a ^ h1a ^ h2b) & kTmask;
                ib[2] = (h0a ^ h1b ^ h2a) & kTmask; ib[3] = (h0a ^ h1b ^ h2b) & kTmask;
                ib[4] = (h0b ^ h1a ^ h2a) & kTmask; ib[5] = (h0b ^ h1a ^ h2b) & kTmask;
                ib[6] = (h0b ^ h1b ^ h2a) & kTmask; ib[7] = (h0b ^ h1b ^ h2b) & kTmask;
            }
            const float wx0 = 1.0f - fx, wx1 = fx;
            const float wy0 = 1.0f - fy, wy1 = fy;
            const float wz0 = 1.0f - fz, wz1 = fz;
            wb[0] = wx0 * wy0 * wz0; wb[1] = wx0 * wy0 * wz1;
            wb[2] = wx0 * wy1 * wz0; wb[3] = wx0 * wy1 * wz1;
            wb[4] = wx1 * wy0 * wz0; wb[5] = wx1 * wy0 * wz1;
            wb[6] = wx1 * wy1 * wz0; wb[7] = wx1 * wy1 * wz1;
        }

        uint32_t ua[8], ub[8];
#pragma unroll
        for (int c = 0; c < 8; ++c) ua[c] = tbl[ia[c]];
#pragma unroll
        for (int c = 0; c < 8; ++c) ub[c] = tbl[ib[c]];
#pragma unroll
        for (int c = 0; c < 8; ++c) {
            a0 = fmaf(wa[c], bfx(ua[c]), a0);
            a1 = fmaf(wa[c], bfy(ua[c]), a1);
            b0 = fmaf(wb[c], bfx(ub[c]), b0);
            b1 = fmaf(wb[c], bfy(ub[c]), b1);
        }
    }
#undef GEOM

    const uint32_t pa = (f32_to_bf16_rne(a1) << 16) | f32_to_bf16_rne(a0);
    const uint32_t pb = (f32_to_bf16_rne(b1) << 16) | f32_to_bf16_rne(b0);
    uint32_t* dst = wsb + (size_t)l * (size_t)P + (size_t)p0;
    if (p0 + 1 < P) {
        *reinterpret_cast<uint2*>(dst) = make_uint2(pa, pb);
    } else {
        *dst = pa;
    }
}

// ---------------------------------------------------------------------------
// wsb[l][p] bf16x2 -> out[p][32] f32, LDS-staged, both sides coalesced.
// ---------------------------------------------------------------------------
__global__ __launch_bounds__(256) void hashgrid_transpose(
    const uint32_t* __restrict__ wsb, float4* __restrict__ out4, int P)
{
    __shared__ uint32_t lds[256 * 17];
    const int tid = threadIdx.x;
    const int base = blockIdx.x * 256;

#pragma unroll
    for (int l = 0; l < kL; ++l) {
        const int p = base + tid;
        const uint32_t v = (p < P) ? wsb[(size_t)l * (size_t)P + (size_t)p] : 0u;
        lds[tid * 17 + l] = v;
    }
    __syncthreads();

    const int nvec = min(P - base, 256) * 8;
#pragma unroll
    for (int j = 0; j < 8; ++j) {
        const int tvec = j * 256 + tid;
        if (tvec < nvec) {
            const int pl = tvec >> 3;
            const int m = tvec & 7;
            const uint32_t ua = lds[pl * 17 + 2 * m];
            const uint32_t ub = lds[pl * 17 + 2 * m + 1];
            out4[(size_t)base * 8 + (size_t)tvec] =
                make_float4(bfx(ua), bfy(ua), bfx(ub), bfy(ub));
        }
    }
}

// ---------------------------------------------------------------------------
// Fallback (monolithic fp32): only if ws too small.
// ---------------------------------------------------------------------------
__global__ __launch_bounds__(256) void hashgrid_fwd_mono(
    const float* __restrict__ x, const float* __restrict__ hashmap,
    float4* __restrict__ out4, int P)
{
    const int p = blockIdx.x * 256 + threadIdx.x;
    if (p >= P) return;
    const float px = x[p * 3 + 0], py = x[p * 3 + 1], pz = x[p * 3 + 2];
    float acc[32];
#pragma unroll
    for (int l = 0; l < kL; ++l) {
        const float fres = (float)kRES[l];
        const float xs0 = px * fres, xs1 = py * fres, xs2 = pz * fres;
        const float fl0 = floorf(xs0), fl1 = floorf(xs1), fl2 = floorf(xs2);
        const float fx = xs0 - fl0, fy = xs1 - fl1, fz = xs2 - fl2;
        const uint32_t i0 = (uint32_t)(int)fl0, i1 = (uint32_t)(int)fl1, i2 = (uint32_t)(int)fl2;
        const uint32_t h0a = i0, h0b = i0 + 1u;
        const uint32_t h1a = i1 * kP1, h1b = (i1 + 1u) * kP1;
        const uint32_t h2a = i2 * kP2, h2b = (i2 + 1u) * kP2;
        uint32_t idx[8];
        idx[0] = (h0a ^ h1a ^ h2a) & kTmask; idx[1] = (h0a ^ h1a ^ h2b) & kTmask;
        idx[2] = (h0a ^ h1b ^ h2a) & kTmask; idx[3] = (h0a ^ h1b ^ h2b) & kTmask;
        idx[4] = (h0b ^ h1a ^ h2a) & kTmask; idx[5] = (h0b ^ h1a ^ h2b) & kTmask;
        idx[6] = (h0b ^ h1b ^ h2a) & kTmask; idx[7] = (h0b ^ h1b ^ h2b) & kTmask;
        const float2* tbl = reinterpret_cast<const float2*>(hashmap) + (size_t)l * kT;
        float2 f[8];
#pragma unroll
        for (int c = 0; c < 8; ++c) f[c] = tbl[idx[c]];
        const float wx0 = 1.0f - fx, wx1 = fx;
        const float wy0 = 1.0f - fy, wy1 = fy;
        const float wz0 = 1.0f - fz, wz1 = fz;
        float w[8];
        w[0] = wx0 * wy0 * wz0; w[1] = wx0 * wy0 * wz1;
        w[2] = wx0 * wy1 * wz0; w[3] = wx0 * wy1 * wz1;
        w[4] = wx1 * wy0 * wz0; w[5] = wx1 * wy0 * wz1;
        w[6] = wx1 * wy1 * wz0; w[7] = wx1 * wy1 * wz1;
        float a0 = 0.0f, a1 = 0.0f;
#pragma unroll
        for (int c = 0; c < 8; ++c) {
            a0 = fmaf(w[c], f[c].x, a0);
            a1 = fmaf(w[c], f[c].y, a1);
        }
        acc[2 * l + 0] = a0; acc[2 * l + 1] = a1;
    }
    float4* dst = out4 + (size_t)p * 8;
#pragma unroll
    for (int j = 0; j < 8; ++j)
        dst[j] = make_float4(acc[4 * j], acc[4 * j + 1], acc[4 * j + 2], acc[4 * j + 3]);
}

extern "C" void kernel_launch(void* const* d_in, const int* in_sizes, int n_in,
                              void* d_out, int out_size, void* d_ws, size_t ws_size,
                              hipStream_t stream) {
    const float* x = (const float*)d_in[0];
    const float* hashmap = (const float*)d_in[1];
    float4* out4 = (float4*)d_out;

    const int P = in_sizes[0] / 3;
    const int block = 256;
    const int grid_p = (P + block - 1) / block;

    // ws layout: [0,32MB) bf16 hash tables | dense tables (~7MB) | wsb results
    const size_t tbl_bytes = (size_t)kL * (size_t)kT * 4u;               // 32 MB
    size_t dense_off[8];
    size_t cur = tbl_bytes;
    for (int l = 0; l < 8; ++l) {
        const size_t R = (size_t)kRES[l];
        const size_t bytes = (l < 7) ? (R + 1) * (R + 1) * R * 8      // dense2
                                     : (R + 1) * (R + 1) * (R + 1) * 4; // dense1
        cur = (cur + 255) & ~(size_t)255;
        dense_off[l] = cur;
        cur += bytes;
    }
    cur = (cur + 255) & ~(size_t)255;
    const size_t wsb_off = cur;
    const size_t need = wsb_off + (size_t)kL * (size_t)P * 4u;
    if (ws_size < need) {
        hashgrid_fwd_mono<<<grid_p, block, 0, stream>>>(x, hashmap, out4, P);
        return;
    }

    char* wsc = (char*)d_ws;
    uint32_t* tbl_bf = (uint32_t*)wsc;
    uint32_t* wsb = (uint32_t*)(wsc + wsb_off);

    // pass 1: bf16-pack the hash tables
    const int npairs = (int)((size_t)kL * (size_t)kT / 2);
    convert_tables<<<(npairs + block - 1) / block, block, 0, stream>>>(
        (const float4*)hashmap, (uint2*)tbl_bf, npairs);

    // pass 2: build dense tables for levels 0-7
#define BUILD2(R, L) build_dense2<R, L><<<(((R+1)*(R+1)*R) + 255) / 256, 256, 0, stream>>>( \
        tbl_bf, (uint2*)(wsc + dense_off[L]))
    BUILD2(16, 0); BUILD2(20, 1); BUILD2(25, 2); BUILD2(32, 3);
    BUILD2(40, 4); BUILD2(50, 5); BUILD2(64, 6);
#undef BUILD2
    build_dense1<80, 7><<<((81 * 81 * 81) + 255) / 256, 256, 0, stream>>>(
        tbl_bf, (uint32_t*)(wsc + dense_off[7]));

    // pass 3: mega level-major gather
    Params16 prm;
    for (int l = 0; l < kL; ++l) {
        prm.res[l] = kRES[l];
        prm.fres[l] = (float)kRES[l];
        if (l < 7)      { prm.mode[l] = MODE_DENSE2; prm.off[l] = dense_off[l]; }
        else if (l == 7){ prm.mode[l] = MODE_DENSE1; prm.off[l] = dense_off[l]; }
        else            { prm.mode[l] = MODE_HASH;
                          prm.off[l] = (size_t)l * (size_t)kT * 4u; }
    }
    const int blocksPerLevel = ((P + 1) / 2 + block - 1) / block;
    hashgrid_levels<<<kL * blocksPerLevel, block, 0, stream>>>(
        x, wsc, wsb, P, blocksPerLevel, prm);

    // pass 4: transpose to [P,32]
    hashgrid_transpose<<<grid_p, block, 0, stream>>>(wsb, out4, P);
}

// Round 14
// 849.716 us; speedup vs baseline: 1.4626x; 1.0371x over previous
//
#include <hip/hip_runtime.h>
#include <cstdint>
#include <cstddef>

namespace {
constexpr int kL = 16;                    // levels
constexpr uint32_t kT = 1u << 19;         // hash table entries per level
constexpr uint32_t kTmask = kT - 1u;
constexpr uint32_t kP1 = 2654435761u;     // spatial hash primes
constexpr uint32_t kP2 = 805459861u;

constexpr int kRES[16] = {16, 20, 25, 32, 40, 50, 64, 80,
                          101, 128, 161, 203, 256, 322, 406, 512};

// level modes
constexpr int MODE_HASH = 0;   // random hash gather (levels 8-15)
constexpr int MODE_DENSE1 = 1; // dense grid, 4B entries (level 7)
constexpr int MODE_DENSE2 = 2; // dense grid, z-paired 8B entries (levels 0-6)
}

__device__ __forceinline__ uint32_t hash3(uint32_t c0, uint32_t c1, uint32_t c2) {
    return (c0 ^ (c1 * kP1) ^ (c2 * kP2)) & kTmask;
}

__device__ __forceinline__ uint32_t f32_to_bf16_rne(float f) {
    const uint32_t u = __float_as_uint(f);
    return (u + 0x7fffu + ((u >> 16) & 1u)) >> 16;
}

// unpack packed bf16x2: low half = feature0, high = feature1
__device__ __forceinline__ float bfx(uint32_t u) { return __uint_as_float(u << 16); }
__device__ __forceinline__ float bfy(uint32_t u) { return __uint_as_float(u & 0xffff0000u); }

// ---------------------------------------------------------------------------
// Pre-pass 1: hashmap [L,T,F] f32 -> packed 2xbf16 per entry (4B).
// ---------------------------------------------------------------------------
__global__ __launch_bounds__(256) void convert_tables(
    const float4* __restrict__ hm4, uint2* __restrict__ tbl_bf, int npairs)
{
    const int i = blockIdx.x * 256 + threadIdx.x;
    if (i >= npairs) return;
    const float4 v = hm4[i];
    uint2 o;
    o.x = (f32_to_bf16_rne(v.y) << 16) | f32_to_bf16_rne(v.x);
    o.y = (f32_to_bf16_rne(v.w) << 16) | f32_to_bf16_rne(v.z);
    tbl_bf[i] = o;
}

// ---------------------------------------------------------------------------
// Pre-pass 2a: dense z-paired table for one coarse level (collision
// semantics preserved exactly: we copy hashed VALUES per corner).
// ---------------------------------------------------------------------------
template <int R, int LVL>
__global__ __launch_bounds__(256) void build_dense2(
    const uint32_t* __restrict__ tbl_bf, uint2* __restrict__ d2)
{
    const int n = (R + 1) * (R + 1) * R;
    const int s = blockIdx.x * 256 + threadIdx.x;
    if (s >= n) return;
    const int c2 = s % R;
    const int t = s / R;
    const int c1 = t % (R + 1);
    const int c0 = t / (R + 1);
    const uint32_t* tbl = tbl_bf + (size_t)LVL * (size_t)kT;
    uint2 o;
    o.x = tbl[hash3((uint32_t)c0, (uint32_t)c1, (uint32_t)c2)];
    o.y = tbl[hash3((uint32_t)c0, (uint32_t)c1, (uint32_t)(c2 + 1))];
    d2[s] = o;
}

// Pre-pass 2b: dense 4B table (level 7).
template <int R, int LVL>
__global__ __launch_bounds__(256) void build_dense1(
    const uint32_t* __restrict__ tbl_bf, uint32_t* __restrict__ d1)
{
    const int n = (R + 1) * (R + 1) * (R + 1);
    const int s = blockIdx.x * 256 + threadIdx.x;
    if (s >= n) return;
    const int c2 = s % (R + 1);
    const int t = s / (R + 1);
    const int c1 = t % (R + 1);
    const int c0 = t / (R + 1);
    const uint32_t* tbl = tbl_bf + (size_t)LVL * (size_t)kT;
    d1[s] = tbl[hash3((uint32_t)c0, (uint32_t)c1, (uint32_t)c2)];
}

// ---------------------------------------------------------------------------
struct Params16 {
    int mode[16];
    int res[16];
    float fres[16];
    unsigned long long off[16];   // byte offset of this level's table in ws
};

// ---------------------------------------------------------------------------
// MEGA level-major pass, 4 points/thread (32 outstanding gathers/wave).
// r13 had VGPR=32 -> compiler couldn't keep even 16 gathers in flight ->
// TA starved (803us vs ~340us issue floor). 4pt + 128-VGPR budget
// (launch_bounds min 4 waves/EU) = deeper clauses; occupancy 32->16
// waves/CU but per-CU outstanding requests ~2x.
// ---------------------------------------------------------------------------
__global__ __launch_bounds__(256, 4) void hashgrid_levels(
    const float* __restrict__ x,         // [P,3]
    const char* __restrict__ wsbase,     // ws base (tables live here)
    uint32_t* __restrict__ wsb,          // [kL][P] packed bf16x2 results
    int P, int blocksPerLevel, Params16 prm)
{
    const int l = blockIdx.x / blocksPerLevel;            // wave-uniform
    const int b = blockIdx.x - l * blocksPerLevel;
    const int t = b * 256 + threadIdx.x;
    const int p0 = 4 * t;
    if (p0 >= P) return;

    const int mode = prm.mode[l];
    const int R = prm.res[l];
    const float fres = prm.fres[l];
    const char* tblb = wsbase + prm.off[l];

    // load 4 points (3x float4, 16B-aligned since p0*12B % 16 == 0)
    float px[4], py[4], pz[4];
    if (p0 + 3 < P) {
        const float4* __restrict__ xp4 =
            reinterpret_cast<const float4*>(x + (size_t)p0 * 3);
        const float4 v0 = xp4[0], v1 = xp4[1], v2 = xp4[2];
        px[0] = v0.x; py[0] = v0.y; pz[0] = v0.z;
        px[1] = v0.w; py[1] = v1.x; pz[1] = v1.y;
        px[2] = v1.z; py[2] = v1.w; pz[2] = v2.x;
        px[3] = v2.y; py[3] = v2.z; pz[3] = v2.w;
    } else {
#pragma unroll
        for (int q = 0; q < 4; ++q) {
            const int pc = (p0 + q < P) ? (p0 + q) : (P - 1);
            px[q] = x[(size_t)pc * 3 + 0];
            py[q] = x[(size_t)pc * 3 + 1];
            pz[q] = x[(size_t)pc * 3 + 2];
        }
    }

    // geometry (fp32 ops match the reference exactly)
    int i0[4], i1[4], i2[4];
    float fx[4], fy[4], fz[4];
#pragma unroll
    for (int q = 0; q < 4; ++q) {
        const float xs0 = px[q] * fres, xs1 = py[q] * fres, xs2 = pz[q] * fres;
        const float fl0 = floorf(xs0), fl1 = floorf(xs1), fl2 = floorf(xs2);
        fx[q] = xs0 - fl0; fy[q] = xs1 - fl1; fz[q] = xs2 - fl2;
        i0[q] = (int)fl0; i1[q] = (int)fl1; i2[q] = (int)fl2;
    }

    float r0[4], r1[4];

    if (mode == MODE_DENSE2) {
        const uint2* __restrict__ d2 = reinterpret_cast<const uint2*>(tblb);
        const int sB = R, sA = R * (R + 1);
        // all 16 8B gathers issued as one clause
        uint2 u[4][4];
#pragma unroll
        for (int q = 0; q < 4; ++q) {
            const int base = (i0[q] * (R + 1) + i1[q]) * R + i2[q];
            u[q][0] = d2[base];
            u[q][1] = d2[base + sB];
            u[q][2] = d2[base + sA];
            u[q][3] = d2[base + sA + sB];
        }
#pragma unroll
        for (int q = 0; q < 4; ++q) {
            const float wx0 = 1.0f - fx[q], wx1 = fx[q];
            const float wy0 = 1.0f - fy[q], wy1 = fy[q];
            const float wz0 = 1.0f - fz[q], wz1 = fz[q];
            const float w00 = wx0 * wy0, w01 = wx0 * wy1;
            const float w10 = wx1 * wy0, w11 = wx1 * wy1;
            float a0 = 0.0f, a1 = 0.0f;
            a0 = fmaf(w00 * wz0, bfx(u[q][0].x), a0); a1 = fmaf(w00 * wz0, bfy(u[q][0].x), a1);
            a0 = fmaf(w00 * wz1, bfx(u[q][0].y), a0); a1 = fmaf(w00 * wz1, bfy(u[q][0].y), a1);
            a0 = fmaf(w01 * wz0, bfx(u[q][1].x), a0); a1 = fmaf(w01 * wz0, bfy(u[q][1].x), a1);
            a0 = fmaf(w01 * wz1, bfx(u[q][1].y), a0); a1 = fmaf(w01 * wz1, bfy(u[q][1].y), a1);
            a0 = fmaf(w10 * wz0, bfx(u[q][2].x), a0); a1 = fmaf(w10 * wz0, bfy(u[q][2].x), a1);
            a0 = fmaf(w10 * wz1, bfx(u[q][2].y), a0); a1 = fmaf(w10 * wz1, bfy(u[q][2].y), a1);
            a0 = fmaf(w11 * wz0, bfx(u[q][3].x), a0); a1 = fmaf(w11 * wz0, bfy(u[q][3].x), a1);
            a0 = fmaf(w11 * wz1, bfx(u[q][3].y), a0); a1 = fmaf(w11 * wz1, bfy(u[q][3].y), a1);
            r0[q] = a0; r1[q] = a1;
        }
    } else {
        const uint32_t* __restrict__ tbl = reinterpret_cast<const uint32_t*>(tblb);
        uint32_t idx[4][8];
        if (mode == MODE_DENSE1) {
            const int sB = R + 1, sA = (R + 1) * (R + 1);
#pragma unroll
            for (int q = 0; q < 4; ++q) {
                const int base = (i0[q] * (R + 1) + i1[q]) * (R + 1) + i2[q];
                idx[q][0] = base;           idx[q][1] = base + 1;
                idx[q][2] = base + sB;      idx[q][3] = base + sB + 1;
                idx[q][4] = base + sA;      idx[q][5] = base + sA + 1;
                idx[q][6] = base + sA + sB; idx[q][7] = base + sA + sB + 1;
            }
        } else {
#pragma unroll
            for (int q = 0; q < 4; ++q) {
                const uint32_t h0a = (uint32_t)i0[q], h0b = h0a + 1u;
                const uint32_t h1a = (uint32_t)i1[q] * kP1, h1b = h1a + kP1;
                const uint32_t h2a = (uint32_t)i2[q] * kP2, h2b = h2a + kP2;
                idx[q][0] = (h0a ^ h1a ^ h2a) & kTmask;
                idx[q][1] = (h0a ^ h1a ^ h2b) & kTmask;
                idx[q][2] = (h0a ^ h1b ^ h2a) & kTmask;
                idx[q][3] = (h0a ^ h1b ^ h2b) & kTmask;
                idx[q][4] = (h0b ^ h1a ^ h2a) & kTmask;
                idx[q][5] = (h0b ^ h1a ^ h2b) & kTmask;
                idx[q][6] = (h0b ^ h1b ^ h2a) & kTmask;
                idx[q][7] = (h0b ^ h1b ^ h2b) & kTmask;
            }
        }
        // all 32 4B gathers issued as one clause
        uint32_t u[4][8];
#pragma unroll
        for (int q = 0; q < 4; ++q) {
#pragma unroll
            for (int c = 0; c < 8; ++c) u[q][c] = tbl[idx[q][c]];
        }
#pragma unroll
        for (int q = 0; q < 4; ++q) {
            const float wx0 = 1.0f - fx[q], wx1 = fx[q];
            const float wy0 = 1.0f - fy[q], wy1 = fy[q];
            const float wz0 = 1.0f - fz[q], wz1 = fz[q];
            float w[8];
            w[0] = wx0 * wy0 * wz0; w[1] = wx0 * wy0 * wz1;
            w[2] = wx0 * wy1 * wz0; w[3] = wx0 * wy1 * wz1;
            w[4] = wx1 * wy0 * wz0; w[5] = wx1 * wy0 * wz1;
            w[6] = wx1 * wy1 * wz0; w[7] = wx1 * wy1 * wz1;
            float a0 = 0.0f, a1 = 0.0f;
#pragma unroll
            for (int c = 0; c < 8; ++c) {
                a0 = fmaf(w[c], bfx(u[q][c]), a0);
                a1 = fmaf(w[c], bfy(u[q][c]), a1);
            }
            r0[q] = a0; r1[q] = a1;
        }
    }

    uint32_t pk[4];
#pragma unroll
    for (int q = 0; q < 4; ++q)
        pk[q] = (f32_to_bf16_rne(r1[q]) << 16) | f32_to_bf16_rne(r0[q]);

    uint32_t* dst = wsb + (size_t)l * (size_t)P + (size_t)p0;
    if (p0 + 3 < P) {
        *reinterpret_cast<uint4*>(dst) = make_uint4(pk[0], pk[1], pk[2], pk[3]);
    } else {
#pragma unroll
        for (int q = 0; q < 4; ++q)
            if (p0 + q < P) dst[q] = pk[q];
    }
}

// ---------------------------------------------------------------------------
// wsb[l][p] bf16x2 -> out[p][32] f32, LDS-staged, both sides coalesced.
// ---------------------------------------------------------------------------
__global__ __launch_bounds__(256) void hashgrid_transpose(
    const uint32_t* __restrict__ wsb, float4* __restrict__ out4, int P)
{
    __shared__ uint32_t lds[256 * 17];
    const int tid = threadIdx.x;
    const int base = blockIdx.x * 256;

#pragma unroll
    for (int l = 0; l < kL; ++l) {
        const int p = base + tid;
        const uint32_t v = (p < P) ? wsb[(size_t)l * (size_t)P + (size_t)p] : 0u;
        lds[tid * 17 + l] = v;
    }
    __syncthreads();

    const int nvec = min(P - base, 256) * 8;
#pragma unroll
    for (int j = 0; j < 8; ++j) {
        const int tvec = j * 256 + tid;
        if (tvec < nvec) {
            const int pl = tvec >> 3;
            const int m = tvec & 7;
            const uint32_t ua = lds[pl * 17 + 2 * m];
            const uint32_t ub = lds[pl * 17 + 2 * m + 1];
            out4[(size_t)base * 8 + (size_t)tvec] =
                make_float4(bfx(ua), bfy(ua), bfx(ub), bfy(ub));
        }
    }
}

// ---------------------------------------------------------------------------
// Fallback (monolithic fp32): only if ws too small.
// ---------------------------------------------------------------------------
__global__ __launch_bounds__(256) void hashgrid_fwd_mono(
    const float* __restrict__ x, const float* __restrict__ hashmap,
    float4* __restrict__ out4, int P)
{
    const int p = blockIdx.x * 256 + threadIdx.x;
    if (p >= P) return;
    const float px = x[p * 3 + 0], py = x[p * 3 + 1], pz = x[p * 3 + 2];
    float acc[32];
#pragma unroll
    for (int l = 0; l < kL; ++l) {
        const float fres = (float)kRES[l];
        const float xs0 = px * fres, xs1 = py * fres, xs2 = pz * fres;
        const float fl0 = floorf(xs0), fl1 = floorf(xs1), fl2 = floorf(xs2);
        const float fx = xs0 - fl0, fy = xs1 - fl1, fz = xs2 - fl2;
        const uint32_t i0 = (uint32_t)(int)fl0, i1 = (uint32_t)(int)fl1, i2 = (uint32_t)(int)fl2;
        const uint32_t h0a = i0, h0b = i0 + 1u;
        const uint32_t h1a = i1 * kP1, h1b = (i1 + 1u) * kP1;
        const uint32_t h2a = i2 * kP2, h2b = (i2 + 1u) * kP2;
        uint32_t idx[8];
        idx[0] = (h0a ^ h1a ^ h2a) & kTmask; idx[1] = (h0a ^ h1a ^ h2b) & kTmask;
        idx[2] = (h0a ^ h1b ^ h2a) & kTmask; idx[3] = (h0a ^ h1b ^ h2b) & kTmask;
        idx[4] = (h0b ^ h1a ^ h2a) & kTmask; idx[5] = (h0b ^ h1a ^ h2b) & kTmask;
        idx[6] = (h0b ^ h1b ^ h2a) & kTmask; idx[7] = (h0b ^ h1b ^ h2b) & kTmask;
        const float2* tbl = reinterpret_cast<const float2*>(hashmap) + (size_t)l * kT;
        float2 f[8];
#pragma unroll
        for (int c = 0; c < 8; ++c) f[c] = tbl[idx[c]];
        const float wx0 = 1.0f - fx, wx1 = fx;
        const float wy0 = 1.0f - fy, wy1 = fy;
        const float wz0 = 1.0f - fz, wz1 = fz;
        float w[8];
        w[0] = wx0 * wy0 * wz0; w[1] = wx0 * wy0 * wz1;
        w[2] = wx0 * wy1 * wz0; w[3] = wx0 * wy1 * wz1;
        w[4] = wx1 * wy0 * wz0; w[5] = wx1 * wy0 * wz1;
        w[6] = wx1 * wy1 * wz0; w[7] = wx1 * wy1 * wz1;
        float a0 = 0.0f, a1 = 0.0f;
#pragma unroll
        for (int c = 0; c < 8; ++c) {
            a0 = fmaf(w[c], f[c].x, a0);
            a1 = fmaf(w[c], f[c].y, a1);
        }
        acc[2 * l + 0] = a0; acc[2 * l + 1] = a1;
    }
    float4* dst = out4 + (size_t)p * 8;
#pragma unroll
    for (int j = 0; j < 8; ++j)
        dst[j] = make_float4(acc[4 * j], acc[4 * j + 1], acc[4 * j + 2], acc[4 * j + 3]);
}

extern "C" void kernel_launch(void* const* d_in, const int* in_sizes, int n_in,
                              void* d_out, int out_size, void* d_ws, size_t ws_size,
                              hipStream_t stream) {
    const float* x = (const float*)d_in[0];
    const float* hashmap = (const float*)d_in[1];
    float4* out4 = (float4*)d_out;

    const int P = in_sizes[0] / 3;
    const int block = 256;
    const int grid_p = (P + block - 1) / block;

    // ws layout: [0,32MB) bf16 hash tables | dense tables (~7MB) | wsb results
    const size_t tbl_bytes = (size_t)kL * (size_t)kT * 4u;               // 32 MB
    size_t dense_off[8];
    size_t cur = tbl_bytes;
    for (int l = 0; l < 8; ++l) {
        const size_t R = (size_t)kRES[l];
        const size_t bytes = (l < 7) ? (R + 1) * (R + 1) * R * 8
                                     : (R + 1) * (R + 1) * (R + 1) * 4;
        cur = (cur + 255) & ~(size_t)255;
        dense_off[l] = cur;
        cur += bytes;
    }
    cur = (cur + 255) & ~(size_t)255;
    const size_t wsb_off = cur;
    const size_t need = wsb_off + (size_t)kL * (size_t)P * 4u;
    if (ws_size < need) {
        hashgrid_fwd_mono<<<grid_p, block, 0, stream>>>(x, hashmap, out4, P);
        return;
    }

    char* wsc = (char*)d_ws;
    uint32_t* tbl_bf = (uint32_t*)wsc;
    uint32_t* wsb = (uint32_t*)(wsc + wsb_off);

    // pass 1: bf16-pack the hash tables
    const int npairs = (int)((size_t)kL * (size_t)kT / 2);
    convert_tables<<<(npairs + block - 1) / block, block, 0, stream>>>(
        (const float4*)hashmap, (uint2*)tbl_bf, npairs);

    // pass 2: build dense tables for levels 0-7
#define BUILD2(R, L) build_dense2<R, L><<<(((R+1)*(R+1)*R) + 255) / 256, 256, 0, stream>>>( \
        tbl_bf, (uint2*)(wsc + dense_off[L]))
    BUILD2(16, 0); BUILD2(20, 1); BUILD2(25, 2); BUILD2(32, 3);
    BUILD2(40, 4); BUILD2(50, 5); BUILD2(64, 6);
#undef BUILD2
    build_dense1<80, 7><<<((81 * 81 * 81) + 255) / 256, 256, 0, stream>>>(
        tbl_bf, (uint32_t*)(wsc + dense_off[7]));

    // pass 3: mega level-major gather, 4 points/thread
    Params16 prm;
    for (int l = 0; l < kL; ++l) {
        prm.res[l] = kRES[l];
        prm.fres[l] = (float)kRES[l];
        if (l < 7)       { prm.mode[l] = MODE_DENSE2; prm.off[l] = dense_off[l]; }
        else if (l == 7) { prm.mode[l] = MODE_DENSE1; prm.off[l] = dense_off[l]; }
        else             { prm.mode[l] = MODE_HASH;
                           prm.off[l] = (size_t)l * (size_t)kT * 4u; }
    }
    const int blocksPerLevel = ((P + 3) / 4 + block - 1) / block;
    hashgrid_levels<<<kL * blocksPerLevel, block, 0, stream>>>(
        x, wsc, wsb, P, blocksPerLevel, prm);

    // pass 4: transpose to [P,32]
    hashgrid_transpose<<<grid_p, block, 0, stream>>>(wsb, out4, P);
}